// Round 5
// baseline (500.149 us; speedup 1.0000x reference)
//
#include <hip/hip_runtime.h>
#include <hip/hip_bf16.h>

typedef __attribute__((ext_vector_type(8))) short short8_t;
typedef __attribute__((ext_vector_type(4))) float f32x4_t;
typedef __attribute__((ext_vector_type(2))) float f32x2_t;

#define NHEAD 4
#define SCALE 0.17677669529663687f

// workspace layout (bytes) — total ~168 MB (proven budget >= 201.8 MB)
#define OFF_W    0L           // weights bf16: qkv(49152) proj(16384) fc1(65536) fc2(65536)
#define OFF_TBL  393216L      // rpe table t[4][225] f32 (head-major)
#define OFF_QKV  458752L      // qkv bf16 [131072][384]
#define OFF_ATTN 101122048L   // attn_out bf16 [131072][128] (dead after proj)
#define OFF_X1BF 134676480L   // x1 bf16 [131072][128] (fused-MLP A + residual)

__device__ __forceinline__ unsigned short f2bf(float f){
  unsigned int u = __float_as_uint(f);
  u += 0x7FFFu + ((u >> 16) & 1u);          // RNE
  return (unsigned short)(u >> 16);
}
__device__ __forceinline__ float bf2f(unsigned short s){
  return __uint_as_float(((unsigned int)s) << 16);
}

// windowed (shifted) row r -> original token index
__device__ __forceinline__ int win_row_to_orig(int r){
  int win = r >> 6, n = r & 63;
  int b = win >> 6, wh = (win >> 3) & 7, ww = win & 7;
  int hs = wh*8 + (n >> 3), wsv = ww*8 + (n & 7);
  return (b << 12) + (((hs + 4) & 63) << 6) + ((wsv + 4) & 63);
}

// exact-GELU via Abramowitz-Stegun 7.1.26 erf (abs err <= 1.5e-7)
__device__ __forceinline__ float gelu_exact(float x){
  float z  = x * 0.70710678118654752f;
  float az = fabsf(z);
  float t  = __builtin_amdgcn_rcpf(1.0f + 0.3275911f * az);
  float poly = t*(0.254829592f + t*(-0.284496736f + t*(1.421413741f +
               t*(-1.453152027f + t*1.061405429f))));
  float er = 1.0f - poly * __expf(-z*z);
  er = (z < 0.f) ? -er : er;
  return 0.5f * x * (1.0f + er);
}

// ---------------- prep: weights -> bf16, RPE MLP table ----------------
__global__ __launch_bounds__(256) void prep_kernel(
    const float* __restrict__ qkv_w, const float* __restrict__ proj_w,
    const float* __restrict__ fc1_w, const float* __restrict__ fc2_w,
    const float* __restrict__ rpe_w1, const float* __restrict__ rpe_b1,
    const float* __restrict__ rpe_w2,
    unsigned short* __restrict__ wbf, float* __restrict__ tbl)
{
  if (blockIdx.x == 0) {
    int t = threadIdx.x;
    if (t < 225) {
      int a = t / 15, b = t % 15;
      float v0 = (float)(a - 7) * (8.0f / 7.0f);
      float v1 = (float)(b - 7) * (8.0f / 7.0f);
      float c0 = (v0 > 0.f ? 1.f : (v0 < 0.f ? -1.f : 0.f)) * log2f(fabsf(v0) + 1.f) * (1.0f/3.0f);
      float c1 = (v1 > 0.f ? 1.f : (v1 < 0.f ? -1.f : 0.f)) * log2f(fabsf(v1) + 1.f) * (1.0f/3.0f);
      float a0 = 0.f, a1 = 0.f, a2 = 0.f, a3 = 0.f;
      for (int k = 0; k < 512; k++){
        float h = c0 * rpe_w1[2*k] + c1 * rpe_w1[2*k+1] + rpe_b1[k];
        h = fmaxf(h, 0.f);
        a0 += h * rpe_w2[k];
        a1 += h * rpe_w2[512 + k];
        a2 += h * rpe_w2[1024 + k];
        a3 += h * rpe_w2[1536 + k];
      }
      tbl[t] = a0; tbl[225 + t] = a1; tbl[450 + t] = a2; tbl[675 + t] = a3;
    }
  } else {
    int e = (blockIdx.x - 1) * 256 + threadIdx.x;   // 0..196607
    float v;
    if (e < 49152)       v = qkv_w[e];
    else if (e < 65536)  v = proj_w[e - 49152];
    else if (e < 131072) v = fc1_w[e - 65536];
    else                 v = fc2_w[e - 131072];
    wbf[e] = f2bf(v);
  }
}

// ---------------- flavor A GEMM: A-panel in registers, B-frags from L2 ----------------
// out[M][N] = A[M][K=128] * W[N][K]^T + bias. 4 waves/block, 64 rows/wave.
// No LDS, no barriers. AMODE: 1 = A f32 + window-gather, 2 = A bf16 direct.
template<int N, int AMODE, int EPI>
__global__ __launch_bounds__(256) void gemm_a_kernel(
    const void* __restrict__ Ap, const unsigned short* __restrict__ Bw,
    const float* __restrict__ bias, unsigned short* __restrict__ Out)
{
  constexpr int K  = 128;
  constexpr int NC = N / 32;
  int lane = threadIdx.x & 63;
  int wave = threadIdx.x >> 6;
  int l15 = lane & 15, kg = lane >> 4;
  int m0 = (blockIdx.x * 4 + wave) * 64;

  short8_t a[4][4];
#pragma unroll
  for (int mr = 0; mr < 4; mr++){
    int r = m0 + mr*16 + l15;
    if (AMODE == 1) r = win_row_to_orig(r);
    if (AMODE == 2){
      const unsigned short* ap = (const unsigned short*)Ap + (long)r * K + kg * 8;
#pragma unroll
      for (int kc = 0; kc < 4; kc++)
        a[mr][kc] = *(const short8_t*)(ap + kc * 32);
    } else {
      const float* ap = (const float*)Ap + (long)r * K + kg * 8;
#pragma unroll
      for (int kc = 0; kc < 4; kc++){
        f32x4_t a0 = *(const f32x4_t*)(ap + kc * 32);
        f32x4_t a1 = *(const f32x4_t*)(ap + kc * 32 + 4);
        union { short8_t v; unsigned short u[8]; } pk;
        pk.u[0] = f2bf(a0[0]); pk.u[1] = f2bf(a0[1]); pk.u[2] = f2bf(a0[2]); pk.u[3] = f2bf(a0[3]);
        pk.u[4] = f2bf(a1[0]); pk.u[5] = f2bf(a1[1]); pk.u[6] = f2bf(a1[2]); pk.u[7] = f2bf(a1[3]);
        a[mr][kc] = pk.v;
      }
    }
  }

  const unsigned short* bp0 = Bw + (long)l15 * K + kg * 8;

#pragma unroll 2
  for (int nc = 0; nc < NC; nc++){
    short8_t b[2][4];
#pragma unroll
    for (int nr = 0; nr < 2; nr++)
#pragma unroll
      for (int kc = 0; kc < 4; kc++)
        b[nr][kc] = *(const short8_t*)(bp0 + (long)(nc*32 + nr*16) * K + kc * 32);

    f32x4_t acc[4][2];
#pragma unroll
    for (int mr = 0; mr < 4; mr++)
#pragma unroll
      for (int nr = 0; nr < 2; nr++) acc[mr][nr] = (f32x4_t){0.f,0.f,0.f,0.f};
#pragma unroll
    for (int kc = 0; kc < 4; kc++)
#pragma unroll
      for (int mr = 0; mr < 4; mr++)
#pragma unroll
        for (int nr = 0; nr < 2; nr++)
          acc[mr][nr] = __builtin_amdgcn_mfma_f32_16x16x32_bf16(a[mr][kc], b[nr][kc], acc[mr][nr], 0, 0, 0);

#pragma unroll
    for (int nr = 0; nr < 2; nr++){
      int col = nc*32 + nr*16 + l15;
      float bv = bias[col];
#pragma unroll
      for (int mr = 0; mr < 4; mr++)
#pragma unroll
        for (int i = 0; i < 4; i++){
          float v = acc[mr][nr][i] + bv;
          if (EPI == 2) v = gelu_exact(v);
          Out[(long)(m0 + mr*16 + kg*4 + i) * N + col] = f2bf(v);
        }
    }
  }
}

// ---------------- flavor B GEMM + fused LayerNorm-residual (proj+LN1) ----------------
template<int K, int SCATTER, int RESBF, int OUTBF>
__global__ __launch_bounds__(256) void gemm_b_ln_kernel(
    const unsigned short* __restrict__ Ap, const unsigned short* __restrict__ Bw,
    const float* __restrict__ bias,
    const float* __restrict__ lnw, const float* __restrict__ lnb,
    const void* __restrict__ Res, void* __restrict__ OutP)
{
  constexpr int KC = K / 32;
  int lane = threadIdx.x & 63;
  int wave = threadIdx.x >> 6;
  int l15 = lane & 15, kg = lane >> 4;
  int m0 = (blockIdx.x * 4 + wave) * 32;

  f32x4_t acc[2][8];
#pragma unroll
  for (int mr = 0; mr < 2; mr++)
#pragma unroll
    for (int nt = 0; nt < 8; nt++) acc[mr][nt] = (f32x4_t){0.f,0.f,0.f,0.f};

  const unsigned short* ap0 = Ap + (long)(m0 + l15) * K + kg * 8;
  const unsigned short* bp0 = Bw + (long)l15 * K + kg * 8;

#pragma unroll 2
  for (int kc = 0; kc < KC; kc++){
    short8_t a0 = *(const short8_t*)(ap0 + kc * 32);
    short8_t a1 = *(const short8_t*)(ap0 + 16 * K + kc * 32);
    short8_t b[8];
#pragma unroll
    for (int nt = 0; nt < 8; nt++)
      b[nt] = *(const short8_t*)(bp0 + (long)nt * 16 * K + kc * 32);
#pragma unroll
    for (int nt = 0; nt < 8; nt++)
      acc[0][nt] = __builtin_amdgcn_mfma_f32_16x16x32_bf16(a0, b[nt], acc[0][nt], 0, 0, 0);
#pragma unroll
    for (int nt = 0; nt < 8; nt++)
      acc[1][nt] = __builtin_amdgcn_mfma_f32_16x16x32_bf16(a1, b[nt], acc[1][nt], 0, 0, 0);
  }

  float bv[8], wv[8], bb[8];
#pragma unroll
  for (int nt = 0; nt < 8; nt++){
    int col = nt*16 + l15;
    bv[nt] = bias[col]; wv[nt] = lnw[col]; bb[nt] = lnb[col];
  }

#pragma unroll
  for (int mr = 0; mr < 2; mr++)
#pragma unroll
    for (int i = 0; i < 4; i++){
      float v[8];
      float s1 = 0.f, s2 = 0.f;
#pragma unroll
      for (int nt = 0; nt < 8; nt++){
        v[nt] = acc[mr][nt][i] + bv[nt];
        s1 += v[nt]; s2 += v[nt]*v[nt];
      }
      s1 += __shfl_xor(s1, 1); s2 += __shfl_xor(s2, 1);
      s1 += __shfl_xor(s1, 2); s2 += __shfl_xor(s2, 2);
      s1 += __shfl_xor(s1, 4); s2 += __shfl_xor(s2, 4);
      s1 += __shfl_xor(s1, 8); s2 += __shfl_xor(s2, 8);
      float mu = s1 * 0.0078125f;
      float var = s2 * 0.0078125f - mu * mu;
      float rs = rsqrtf(var + 1e-5f);
      int row = m0 + mr*16 + kg*4 + i;
      int orow = SCATTER ? win_row_to_orig(row) : row;
      long rb = (long)orow * 128;
#pragma unroll
      for (int nt = 0; nt < 8; nt++){
        int col = nt*16 + l15;
        float r = RESBF ? bf2f(((const unsigned short*)Res)[rb + col])
                        : ((const float*)Res)[rb + col];
        float o = r + (v[nt] - mu) * rs * wv[nt] + bb[nt];
        if (OUTBF) ((unsigned short*)OutP)[rb + col] = f2bf(o);
        else       ((float*)OutP)[rb + col] = o;
      }
    }
}

// ---------------- fused MLP: fc1 + GELU -> LDS h -> fc2 + LN2 + residual ----------------
// block = 64 rows, 4 waves. Phase 1: wave owns a 128-col chunk of h[64][512];
// A-panel in regs, fc1_w frags from L2; GELU; h -> LDS with XOR swizzle
// (group ^= row&7) so phase-2 ds_read_b128 frag reads are conflict-free.
// Phase 2: wave owns 16 rows; A from LDS, fc2_w frags from L2; LN2+res epilogue.
__global__ __launch_bounds__(256) void fused_mlp_kernel(
    const unsigned short* __restrict__ x1, const unsigned short* __restrict__ W1,
    const float* __restrict__ b1, const unsigned short* __restrict__ W2,
    const float* __restrict__ b2,
    const float* __restrict__ lnw, const float* __restrict__ lnb,
    float* __restrict__ out)
{
  __shared__ __align__(16) unsigned short hl[64 * 512];   // 64 KB
  int lane = threadIdx.x & 63;
  int wave = threadIdx.x >> 6;
  int l15 = lane & 15, kg = lane >> 4;
  int m0 = blockIdx.x * 64;

  // ---- phase 1: h chunk [64 rows][cols wave*128 .. +128] ----
  short8_t a[4][4];
#pragma unroll
  for (int mr = 0; mr < 4; mr++){
    const unsigned short* ap = x1 + (long)(m0 + mr*16 + l15) * 128 + kg * 8;
#pragma unroll
    for (int kc = 0; kc < 4; kc++)
      a[mr][kc] = *(const short8_t*)(ap + kc * 32);
  }

#pragma unroll
  for (int nc = 0; nc < 2; nc++){
    short8_t b[4][4];
#pragma unroll
    for (int nr = 0; nr < 4; nr++){
      const unsigned short* bp = W1 + (long)(wave*128 + nc*64 + nr*16 + l15) * 128 + kg * 8;
#pragma unroll
      for (int kc = 0; kc < 4; kc++)
        b[nr][kc] = *(const short8_t*)(bp + kc * 32);
    }
    f32x4_t acc[4][4];
#pragma unroll
    for (int mr = 0; mr < 4; mr++)
#pragma unroll
      for (int nr = 0; nr < 4; nr++) acc[mr][nr] = (f32x4_t){0.f,0.f,0.f,0.f};
#pragma unroll
    for (int kc = 0; kc < 4; kc++)
#pragma unroll
      for (int mr = 0; mr < 4; mr++)
#pragma unroll
        for (int nr = 0; nr < 4; nr++)
          acc[mr][nr] = __builtin_amdgcn_mfma_f32_16x16x32_bf16(a[mr][kc], b[nr][kc], acc[mr][nr], 0, 0, 0);

#pragma unroll
    for (int nr = 0; nr < 4; nr++){
      int col = wave*128 + nc*64 + nr*16 + l15;
      float bv = b1[col];
      int gbase = col >> 3, glo = col & 7;
#pragma unroll
      for (int mr = 0; mr < 4; mr++)
#pragma unroll
        for (int i = 0; i < 4; i++){
          int row = mr*16 + kg*4 + i;
          float v = gelu_exact(acc[mr][nr][i] + bv);
          hl[row * 512 + ((gbase ^ (row & 7)) << 3) + glo] = f2bf(v);
        }
    }
  }
  __syncthreads();

  // ---- phase 2: y rows [wave*16 .. +16] = h * W2^T ----
  f32x4_t acc2[8];
#pragma unroll
  for (int nt = 0; nt < 8; nt++) acc2[nt] = (f32x4_t){0.f,0.f,0.f,0.f};

  int r = wave*16 + l15;                 // local row; r&7 == l15&7
  const unsigned short* hrow = hl + r * 512;

#pragma unroll 2
  for (int kc = 0; kc < 16; kc++){
    int g = (kc*4 + kg) ^ (l15 & 7);
    short8_t a2 = *(const short8_t*)(hrow + (g << 3));
    short8_t bb[8];
#pragma unroll
    for (int nt = 0; nt < 8; nt++)
      bb[nt] = *(const short8_t*)(W2 + (long)(nt*16 + l15) * 512 + kc*32 + kg*8);
#pragma unroll
    for (int nt = 0; nt < 8; nt++)
      acc2[nt] = __builtin_amdgcn_mfma_f32_16x16x32_bf16(a2, bb[nt], acc2[nt], 0, 0, 0);
  }

  float bv[8], wv[8], bbv[8];
#pragma unroll
  for (int nt = 0; nt < 8; nt++){
    int col = nt*16 + l15;
    bv[nt] = b2[col]; wv[nt] = lnw[col]; bbv[nt] = lnb[col];
  }
#pragma unroll
  for (int i = 0; i < 4; i++){
    float v[8];
    float s1 = 0.f, s2 = 0.f;
#pragma unroll
    for (int nt = 0; nt < 8; nt++){
      v[nt] = acc2[nt][i] + bv[nt];
      s1 += v[nt]; s2 += v[nt]*v[nt];
    }
    s1 += __shfl_xor(s1, 1); s2 += __shfl_xor(s2, 1);
    s1 += __shfl_xor(s1, 2); s2 += __shfl_xor(s2, 2);
    s1 += __shfl_xor(s1, 4); s2 += __shfl_xor(s2, 4);
    s1 += __shfl_xor(s1, 8); s2 += __shfl_xor(s2, 8);
    float mu = s1 * 0.0078125f;
    float var = s2 * 0.0078125f - mu * mu;
    float rs = rsqrtf(var + 1e-5f);
    long rb = (long)(m0 + wave*16 + kg*4 + i) * 128;
#pragma unroll
    for (int nt = 0; nt < 8; nt++){
      int col = nt*16 + l15;
      float res = bf2f(x1[rb + col]);
      out[rb + col] = res + (v[nt] - mu) * rs * wv[nt] + bbv[nt];
    }
  }
}

// ---------------- per-window attention, MFMA (unchanged) ----------------
__global__ __launch_bounds__(256) void attn_kernel(
    const unsigned short* __restrict__ qkv, const float* __restrict__ tbl,
    unsigned short* __restrict__ outp)
{
  __shared__ __align__(16) unsigned short vt[NHEAD][32][72];
  __shared__ __align__(16) unsigned short pl[NHEAD][16][72];
  __shared__ float tl[900];
  int win  = blockIdx.x;
  int head = threadIdx.x >> 6;
  int lane = threadIdx.x & 63;
  int l15 = lane & 15, kg = lane >> 4;

  for (int e = threadIdx.x; e < 900; e += 256) tl[e] = tbl[e];

  const unsigned short* qbase = qkv + (long)win * 64 * 384;

  {
    const unsigned short* vp = qbase + lane * 384 + 256 + head * 32;
#pragma unroll
    for (int d0 = 0; d0 < 4; d0++){
      union { short8_t v; unsigned short u[8]; } pk;
      pk.v = *(const short8_t*)(vp + d0 * 8);
#pragma unroll
      for (int j = 0; j < 8; j++)
        vt[head][d0 * 8 + j][lane] = pk.u[j];
    }
  }

  short8_t kf[4];
#pragma unroll
  for (int nt = 0; nt < 4; nt++)
    kf[nt] = *(const short8_t*)(qbase + (nt * 16 + l15) * 384 + 128 + head * 32 + kg * 8);

  __syncthreads();

  short8_t bvf[2][2];
#pragma unroll
  for (int dt = 0; dt < 2; dt++)
#pragma unroll
    for (int ks = 0; ks < 2; ks++)
      bvf[dt][ks] = *(const short8_t*)(&vt[head][dt * 16 + l15][ks * 32 + kg * 8]);

  const float* tlh = tl + head * 225;
  bool wh7 = ((win >> 3) & 7) == 7;
  bool ww7 = (win & 7) == 7;
  bool crq_lt = (kg & 1) == 0;
  bool crm_lt = (l15 & 7) < 4;
  int  t3m_lo = l15 >> 3;
  int  dj0 = (kg & 1) * 4 - (l15 & 7) + 7;

#pragma unroll
  for (int mt = 0; mt < 4; mt++){
    short8_t qf = *(const short8_t*)(qbase + (mt * 16 + l15) * 384 + head * 32 + kg * 8);
    f32x4_t sacc[4];
#pragma unroll
    for (int nt = 0; nt < 4; nt++)
      sacc[nt] = __builtin_amdgcn_mfma_f32_16x16x32_bf16(qf, kf[nt], (f32x4_t){0.f,0.f,0.f,0.f}, 0, 0, 0);

    int t3q = mt * 2 + (kg >> 1);
    bool rrq_lt = t3q < 4;
    float p[4][4];
#pragma unroll
    for (int nt = 0; nt < 4; nt++){
      int t3m = nt * 2 + t3m_lo;
      const float* bp = tlh + (t3q - t3m + 7) * 15 + dj0;
      bool masked = (wh7 && (rrq_lt != (t3m < 4))) || (ww7 && (crq_lt != crm_lt));
      float mterm = masked ? -100.f : 0.f;
#pragma unroll
      for (int ii = 0; ii < 4; ii++){
        float s = sacc[nt][ii] * SCALE + bp[ii] + mterm;
        p[nt][ii] = __expf(s);
      }
    }
    float inv[4];
#pragma unroll
    for (int ii = 0; ii < 4; ii++){
      float sm = (p[0][ii] + p[1][ii]) + (p[2][ii] + p[3][ii]);
      sm += __shfl_xor(sm, 1); sm += __shfl_xor(sm, 2);
      sm += __shfl_xor(sm, 4); sm += __shfl_xor(sm, 8);
      inv[ii] = 1.f / sm;
    }
#pragma unroll
    for (int nt = 0; nt < 4; nt++)
#pragma unroll
      for (int ii = 0; ii < 4; ii++)
        pl[head][kg * 4 + ii][nt * 16 + l15] = f2bf(p[nt][ii]);

    asm volatile("s_waitcnt lgkmcnt(0)" ::: "memory");

    f32x4_t oacc[2] = {{0.f,0.f,0.f,0.f},{0.f,0.f,0.f,0.f}};
#pragma unroll
    for (int ks = 0; ks < 2; ks++){
      short8_t pa = *(const short8_t*)(&pl[head][l15][ks * 32 + kg * 8]);
#pragma unroll
      for (int dt = 0; dt < 2; dt++)
        oacc[dt] = __builtin_amdgcn_mfma_f32_16x16x32_bf16(pa, bvf[dt][ks], oacc[dt], 0, 0, 0);
    }

    unsigned short* op = outp + ((long)(win * 64 + mt * 16 + kg * 4)) * 128 + head * 32;
#pragma unroll
    for (int ii = 0; ii < 4; ii++)
#pragma unroll
      for (int dt = 0; dt < 2; dt++)
        op[ii * 128 + dt * 16 + l15] = f2bf(oacc[dt][ii] * inv[ii]);
  }
}

extern "C" void kernel_launch(void* const* d_in, const int* in_sizes, int n_in,
                              void* d_out, int out_size, void* d_ws, size_t ws_size,
                              hipStream_t stream)
{
  (void)in_sizes; (void)n_in; (void)out_size; (void)ws_size;
  const float* x      = (const float*)d_in[0];
  const float* qkv_w  = (const float*)d_in[1];
  const float* qkv_b  = (const float*)d_in[2];
  const float* proj_w = (const float*)d_in[3];
  const float* proj_b = (const float*)d_in[4];
  const float* rpe_w1 = (const float*)d_in[5];
  const float* rpe_b1 = (const float*)d_in[6];
  const float* rpe_w2 = (const float*)d_in[7];
  const float* n1w    = (const float*)d_in[8];
  const float* n1b    = (const float*)d_in[9];
  const float* fc1_w  = (const float*)d_in[10];
  const float* fc1_b  = (const float*)d_in[11];
  const float* fc2_w  = (const float*)d_in[12];
  const float* fc2_b  = (const float*)d_in[13];
  const float* n2w    = (const float*)d_in[14];
  const float* n2b    = (const float*)d_in[15];

  char* ws = (char*)d_ws;
  unsigned short* Wbf   = (unsigned short*)(ws + OFF_W);
  float*          tblp  = (float*)(ws + OFF_TBL);
  unsigned short* qkvp  = (unsigned short*)(ws + OFF_QKV);
  unsigned short* attnp = (unsigned short*)(ws + OFF_ATTN);
  unsigned short* x1bf  = (unsigned short*)(ws + OFF_X1BF);

  prep_kernel<<<769, 256, 0, stream>>>(qkv_w, proj_w, fc1_w, fc2_w, rpe_w1, rpe_b1, rpe_w2, Wbf, tblp);
  // QKV: gather x through roll+window, A f32 -> bf16 in-reg, out windowed order
  gemm_a_kernel<384, 1, 0><<<512, 256, 0, stream>>>(x, Wbf, qkv_b, qkvp);
  attn_kernel<<<2048, 256, 0, stream>>>(qkvp, tblp, attnp);
  // proj + LN1 + residual(x), scatter to orig rows, out bf16 x1
  gemm_b_ln_kernel<128, 1, 0, 1><<<1024, 256, 0, stream>>>(
      attnp, Wbf + 49152, proj_b, n1w, n1b, x, x1bf);
  // fused MLP: fc1 + GELU (LDS h) + fc2 + LN2 + residual -> d_out f32
  fused_mlp_kernel<<<2048, 256, 0, stream>>>(
      x1bf, Wbf + 65536, fc1_b, Wbf + 131072, fc2_b, n2w, n2b, (float*)d_out);
}